// Round 7
// baseline (85.868 us; speedup 1.0000x reference)
//
#include <hip/hip_runtime.h>
#include <hip/hip_bf16.h>

#define M_PTS 16384
#define N_SPT 16384
#define DIM   64
#define NSL   32                 // n-slices (2048 blocks -> ~7 waves/SIMD)
#define SLN   (N_SPT / NSL)      // 512 n-rows per block
#define TSTEPS (SLN / 16)        // 32 MFMA steps per block

typedef __attribute__((ext_vector_type(8))) short bf16x8;
typedef __attribute__((ext_vector_type(4))) float f32x4;

#define LOG2E 1.4426950408889634f

__device__ __forceinline__ unsigned short f32_bf16_rne(float f) {
  unsigned int x = __float_as_uint(f);
  x = x + 0x7fffu + ((x >> 16) & 1u);
  return (unsigned short)(x >> 16);
}
__device__ __forceinline__ float bf16_f32(unsigned short u) {
  return __uint_as_float(((unsigned int)u) << 16);
}

// Prep (unchanged, known-good):
//  points : store p~ = bf16(scale * p); Em = exp2(-|p~|^2/(2*scale))
//  spatial: store s~ = bf16(s); En = w * exp2(-|s~|^2 * scale/2)
// Em*En*exp2(p~ . s~) == exact Gaussian of the rounded points.
__global__ __launch_bounds__(256) void kde_prep(
    const float* __restrict__ pts, const float* __restrict__ spt,
    const float* __restrict__ w, const float* __restrict__ bw,
    unsigned short* __restrict__ ptsb, unsigned short* __restrict__ spb,
    float* __restrict__ Em, float* __restrict__ En) {
  const float b = bw[0];
  const float scale = LOG2E / (b * b);
  const float c1 = 0.5f * scale;
  const float invc = (b * b) / (2.0f * LOG2E);
  const int tid = threadIdx.x;
  const bool isP = blockIdx.x < (M_PTS / 16);
  const int r0 = isP ? (blockIdx.x * 16) : ((blockIdx.x - M_PTS / 16) * 16);
  const float* __restrict__ src = isP ? pts : spt;
  unsigned short* __restrict__ dst = isP ? ptsb : spb;

  size_t off = (size_t)r0 * DIM + (size_t)tid * 4;
  float4 v = *reinterpret_cast<const float4*>(src + off);
  if (isP) { v.x *= scale; v.y *= scale; v.z *= scale; v.w *= scale; }
  ushort4 u;
  u.x = f32_bf16_rne(v.x); u.y = f32_bf16_rne(v.y);
  u.z = f32_bf16_rne(v.z); u.w = f32_bf16_rne(v.w);
  float ax = bf16_f32(u.x), ay = bf16_f32(u.y);
  float az = bf16_f32(u.z), aw = bf16_f32(u.w);
  float sq = ax * ax + ay * ay + az * az + aw * aw;
  *reinterpret_cast<ushort4*>(dst + off) = u;

  sq += __shfl_xor(sq, 1);
  sq += __shfl_xor(sq, 2);
  sq += __shfl_xor(sq, 4);
  sq += __shfl_xor(sq, 8);
  if ((tid & 15) == 0) {
    int row = r0 + (tid >> 4);
    if (isP) Em[row] = exp2f(-sq * invc);
    else     En[row] = w[row] * exp2f(-sq * c1);
  }
}

// Main v8 = v2 (PASSED, 68 VGPR, barrier-free direct-global) with NSL 16->32.
// Theory: every grid so far was 1024 blocks = exactly 4 waves/SIMD; all six
// ILP-side restructurings (v2..v7) were null or worse, and v6 (2 waves/SIMD)
// scaled wall by 1.6x -> the kernel is TLP-starved, not ILP-starved. 2048
// blocks at 68 VGPR / 2KB LDS -> ~7 waves/SIMD; co-resident waves hide the
// per-step L2 latency that sank v2, and the VALU (exp+fma, the dominant
// pipe at ~20us of total work) approaches saturation.
__global__ __launch_bounds__(256) void kde_main(
    const unsigned short* __restrict__ ptsb,
    const unsigned short* __restrict__ spb,
    const float* __restrict__ En,
    float* __restrict__ partials) {
  __shared__ float lden[SLN];  // 2 KB, read-only after one barrier

  const int tid = threadIdx.x;
  const int lane = tid & 63;
  const int wave = tid >> 6;
  const int lr = lane & 15;   // tile row (A) / tile col (B)
  const int lg = lane >> 4;   // k-group

  const int lid = blockIdx.x;
  const int s = lid >> 6;     // 32 slices; 64 consecutive blocks share one
  const int mb = lid & 63;    //  spb slice (64 KB, L2-resident everywhere)
  const int mbase = mb * 256 + wave * 64;

#pragma unroll
  for (int k = 0; k < SLN / 256; ++k)
    lden[tid + k * 256] = En[s * SLN + tid + k * 256];

  // A fragments (read once; 32 VGPRs).
  bf16x8 a[4][2];
#pragma unroll
  for (int t = 0; t < 4; ++t)
#pragma unroll
    for (int h = 0; h < 2; ++h)
      a[t][h] = *reinterpret_cast<const bf16x8*>(
          ptsb + (size_t)(mbase + t * 16 + lr) * DIM + h * 32 + lg * 8);

  __syncthreads();  // lden ready; no further barriers

  // Per-lane B pointer: step st fragment b0 at st*2048 + lr*128 + lg*16,
  // b1 at +64 bytes.
  const char* bptr =
      (const char*)(spb + (size_t)s * SLN * DIM) + lr * 128 + lg * 16;
  const float* enr = lden + lr;

  const f32x4 kz = {0.0f, 0.0f, 0.0f, 0.0f};  // shared C-init quad
  float sum[4][4] = {{0.0f, 0.0f, 0.0f, 0.0f}, {0.0f, 0.0f, 0.0f, 0.0f},
                     {0.0f, 0.0f, 0.0f, 0.0f}, {0.0f, 0.0f, 0.0f, 0.0f}};
  f32x4 cA[4], cB[4];

#define MS(C, B0, B1)                                                        \
  {                                                                          \
    _Pragma("unroll") for (int t = 0; t < 4; ++t) {                          \
      C[t] = __builtin_amdgcn_mfma_f32_16x16x32_bf16(a[t][0], B0, kz,        \
                                                     0, 0, 0);               \
      C[t] = __builtin_amdgcn_mfma_f32_16x16x32_bf16(a[t][1], B1, C[t],      \
                                                     0, 0, 0);               \
    }                                                                        \
  }

#define FIN(C, EN)                                                           \
  {                                                                          \
    float en = (EN);                                                         \
    _Pragma("unroll") for (int t = 0; t < 4; ++t) {                          \
      _Pragma("unroll") for (int rr = 0; rr < 4; ++rr) {                     \
        float e;                                                             \
        asm("v_exp_f32 %0, %1" : "=v"(e) : "v"(C[t][rr]));                   \
        sum[t][rr] = fmaf(en, e, sum[t][rr]);                                \
      }                                                                      \
    }                                                                        \
  }

  // 1-step register double-buffer (E/O), exactly as the passing v2. Deeper
  // named prefetch is futile (v5: scheduler sinks the loads to their uses);
  // latency hiding now comes from ~7 co-resident waves/SIMD instead.
  bf16x8 e0, e1, o0, o1;
  e0 = *reinterpret_cast<const bf16x8*>(bptr);
  e1 = *reinterpret_cast<const bf16x8*>(bptr + 64);
  o0 = *reinterpret_cast<const bf16x8*>(bptr + 2048);
  o1 = *reinterpret_cast<const bf16x8*>(bptr + 2048 + 64);

  // Peeled steps 0,1 (no FIN for step -1).
  MS(cA, e0, e1)
  e0 = *reinterpret_cast<const bf16x8*>(bptr + 2 * 2048);
  e1 = *reinterpret_cast<const bf16x8*>(bptr + 2 * 2048 + 64);
  MS(cB, o0, o1)
  FIN(cA, enr[0])
  o0 = *reinterpret_cast<const bf16x8*>(bptr + 3 * 2048);
  o1 = *reinterpret_cast<const bf16x8*>(bptr + 3 * 2048 + 64);

  // Steady state: steps 2u,2u+1; loads for 2u+2,2u+3. Final iteration's
  // loads (st 32,33) overread ~4 KB past the s==31 slice into the Em
  // workspace buffer -> benign (same pattern as the passing v2).
  const char* bp = bptr + 4 * 2048;
  for (int u = 1; u < TSTEPS / 2; ++u, bp += 2 * 2048) {
    MS(cA, e0, e1)
    FIN(cB, enr[(2 * u - 1) * 16])
    e0 = *reinterpret_cast<const bf16x8*>(bp);
    e1 = *reinterpret_cast<const bf16x8*>(bp + 64);
    MS(cB, o0, o1)
    FIN(cA, enr[(2 * u) * 16])
    o0 = *reinterpret_cast<const bf16x8*>(bp + 2048);
    o1 = *reinterpret_cast<const bf16x8*>(bp + 2048 + 64);
  }
  FIN(cB, enr[(TSTEPS - 1) * 16])
#undef MS
#undef FIN

  // Reduce the 16 n-columns held across lanes of each k-group.
#pragma unroll
  for (int t = 0; t < 4; ++t)
#pragma unroll
    for (int r = 0; r < 4; ++r) {
      float v = sum[t][r];
      v += __shfl_xor(v, 1);
      v += __shfl_xor(v, 2);
      v += __shfl_xor(v, 4);
      v += __shfl_xor(v, 8);
      sum[t][r] = v;
    }
  if (lr == 0) {
#pragma unroll
    for (int t = 0; t < 4; ++t)
#pragma unroll
      for (int r = 0; r < 4; ++r) {
        int row = mbase + t * 16 + lg * 4 + r;
        partials[(size_t)s * M_PTS + row] = sum[t][r];
      }
  }
}

__global__ __launch_bounds__(256) void kde_reduce(
    const float* __restrict__ partials, const float* __restrict__ Em,
    float* __restrict__ out) {
  int m = blockIdx.x * 256 + threadIdx.x;
  float t = 0.0f;
#pragma unroll
  for (int s2 = 0; s2 < NSL; ++s2)
    t += partials[(size_t)s2 * M_PTS + m];
  out[m] = Em[m] * t;
}

extern "C" void kernel_launch(void* const* d_in, const int* in_sizes, int n_in,
                              void* d_out, int out_size, void* d_ws, size_t ws_size,
                              hipStream_t stream) {
  const float* pts = (const float*)d_in[0];   // [M, 64]
  const float* spt = (const float*)d_in[1];   // [N, 64]
  const float* w   = (const float*)d_in[2];   // [N]
  const float* bw  = (const float*)d_in[3];   // scalar
  float* out = (float*)d_out;                 // [M] fp32

  // ws: ptsb 2MB | spb 2MB | Em 64KB | En 64KB | partials 2MB (~6.2 MB)
  // (Em immediately after spb absorbs the benign tail prefetch overread.)
  char* ws = (char*)d_ws;
  unsigned short* ptsb = (unsigned short*)ws;
  unsigned short* spb  = (unsigned short*)(ws + (size_t)M_PTS * DIM * 2);
  float* Em = (float*)(ws + (size_t)(M_PTS + N_SPT) * DIM * 2);
  float* En = Em + M_PTS;
  float* partials = En + N_SPT;

  kde_prep<<<dim3((M_PTS + N_SPT) / 16), 256, 0, stream>>>(
      pts, spt, w, bw, ptsb, spb, Em, En);
  kde_main<<<dim3(M_PTS / 256 * NSL), 256, 0, stream>>>(
      ptsb, spb, En, partials);
  kde_reduce<<<dim3(M_PTS / 256), 256, 0, stream>>>(partials, Em, out);
}